// Round 1
// baseline (314.478 us; speedup 1.0000x reference)
//
#include <hip/hip_runtime.h>

// SpecAugment: B=64, C=2, F=128, T=2048, fp32.
// out[b,c,f,t] = apply[b] ? (keep[b,f,t] ? spec : 0) + noise*0.01 : spec
//
// V2 structure: grid = (64 blocks, B=64 batches), 256 threads, 8 float4/thread.
//  - blockIdx.y = b  -> apply/mask params are block-uniform, loaded once per
//    thread and amortized over 8 vectors (was 9 tiny loads per 16 B).
//  - All 8 (16 with noise) 16B loads issued before first use -> deep MLP;
//    the old one-shot 1-float4/thread kernel had ~1.5 loads in flight per
//    wave and sat at 42% of achievable HBM BW.
//  - Thread's 8 vecs stride by 16384 float4s: tv (time offset) is invariant
//    -> time mask computed once per thread; f advances by 32 per step.
//  - Non-applied batches: pure unrolled copy, no noise read, no mask math.
//  - out is write-once/never-read -> non-temporal stores keep the write
//    stream from evicting spec+noise (exactly 256 MiB = LLC size).

#define BB 64
#define CC 2
#define FF 128
#define TT 2048
#define VB (CC * FF * (TT / 4))   // 131072 float4 per batch
#define BLOCKS_X 64               // threads per batch = 64*256 = 16384
#define VPB 8                     // float4 per thread
#define STRIDE 16384              // thread stride in float4s (= threads/batch)

typedef float f32x4 __attribute__((ext_vector_type(4)));

__global__ __launch_bounds__(256) void specaug_kernel(
    const float* __restrict__ spec,
    const float* __restrict__ apply_u,
    const float* __restrict__ f_width_u,
    const float* __restrict__ f_start_u,
    const float* __restrict__ t_width_u,
    const float* __restrict__ t_start_u,
    const float* __restrict__ noise,
    float* __restrict__ out)
{
    const int b   = blockIdx.y;
    const int tid = blockIdx.x * blockDim.x + threadIdx.x;   // 0..16383
    const int base = b * VB + tid;                           // float4 index

    const f32x4* __restrict__ sp = (const f32x4*)spec;
    const f32x4* __restrict__ np = (const f32x4*)noise;
    f32x4* __restrict__ op = (f32x4*)out;

    // Block-uniform branch (whole block is one batch): non-applied batches
    // are a straight copy -- no noise read, no mask math.
    if (apply_u[b] > 0.5f) {
        f32x4 v[VPB];
        #pragma unroll
        for (int j = 0; j < VPB; ++j) v[j] = sp[base + j * STRIDE];
        #pragma unroll
        for (int j = 0; j < VPB; ++j)
            __builtin_nontemporal_store(v[j], &op[base + j * STRIDE]);
        return;
    }

    // ---- applied path ----
    // Mask params (identical math to reference; freq range needs no clamp:
    // F - w >= 109 > 0 always; time range clamped to >= 1).
    int fs[2], fw[2], ts[2], tw[2];
    #pragma unroll
    for (int k = 0; k < 2; ++k) {
        fw[k] = (int)floorf(f_width_u[b * 2 + k] * 20.0f);
        fs[k] = (int)floorf(f_start_u[b * 2 + k] * (float)(FF - fw[k]));
        tw[k] = (int)floorf(t_width_u[b * 2 + k] * 40.0f);
        ts[k] = (int)floorf(t_start_u[b * 2 + k] *
                            fmaxf((float)(TT - tw[k]), 1.0f));
    }

    // Time mask: tv = tid & 511 is invariant across the 8 strided vecs
    // (STRIDE is a multiple of 512), so compute the 4-bit mask once.
    const int t0 = (tid & (TT / 4 - 1)) << 2;
    bool tm[4];
    #pragma unroll
    for (int jj = 0; jj < 4; ++jj) {
        const int t = t0 + jj;
        tm[jj] = ((t >= ts[0]) & (t < ts[0] + tw[0])) |
                 ((t >= ts[1]) & (t < ts[1] + tw[1]));
    }

    // Issue all 16 loads before any use -> deep memory-level parallelism.
    f32x4 sv[VPB], nv[VPB];
    #pragma unroll
    for (int j = 0; j < VPB; ++j) sv[j] = sp[base + j * STRIDE];
    #pragma unroll
    for (int j = 0; j < VPB; ++j) nv[j] = np[base + j * STRIDE];

    const int f0 = tid >> 9;   // row group 0..31; f_j = (f0 + 32j) & 127
    #pragma unroll
    for (int j = 0; j < VPB; ++j) {
        const int f = (f0 + 32 * j) & (FF - 1);
        const bool fm = ((f >= fs[0]) & (f < fs[0] + fw[0])) |
                        ((f >= fs[1]) & (f < fs[1] + fw[1]));
        f32x4 o;
        #pragma unroll
        for (int jj = 0; jj < 4; ++jj) {
            const bool keep = !(fm | tm[jj]);
            o[jj] = (keep ? sv[j][jj] : 0.0f) + nv[j][jj] * 0.01f;
        }
        __builtin_nontemporal_store(o, &op[base + j * STRIDE]);
    }
}

extern "C" void kernel_launch(void* const* d_in, const int* in_sizes, int n_in,
                              void* d_out, int out_size, void* d_ws, size_t ws_size,
                              hipStream_t stream) {
    const float* spec      = (const float*)d_in[0];
    const float* apply_u   = (const float*)d_in[1];
    const float* f_width_u = (const float*)d_in[2];
    const float* f_start_u = (const float*)d_in[3];
    const float* t_width_u = (const float*)d_in[4];
    const float* t_start_u = (const float*)d_in[5];
    const float* noise     = (const float*)d_in[6];
    float* out             = (float*)d_out;

    dim3 grid(BLOCKS_X, BB);   // 64 x 64 = 4096 blocks
    specaug_kernel<<<grid, 256, 0, stream>>>(
        spec, apply_u, f_width_u, f_start_u, t_width_u, t_start_u, noise, out);
}

// Round 2
// 307.293 us; speedup vs baseline: 1.0234x; 1.0234x over previous
//
#include <hip/hip_runtime.h>

// SpecAugment: B=64, C=2, F=128, T=2048, fp32.
// out[b,c,f,t] = apply[b] ? (keep[b,f,t] ? spec : 0) + noise*0.01 : spec
//
// V3: contiguous streaming + forced MLP + scalar params.
//  - grid (128, 64): blockIdx.y = batch -> apply/mask params are wave-uniform
//    scalar loads; non-applied batches take a pure-copy path (no noise read).
//  - Each block owns a CONTIGUOUS 16 KB chunk (1024 float4); thread j-vectors
//    at +j*256 stay inside the chunk (V2's 256 KB-strided streams regressed
//    DRAM locality -> reverted).
//  - asm memory fence between the load group and the store group: compiler
//    may NOT sink loads into the store loop (V2 showed it does: VGPR=32
//    proved only ~2 loads in flight). Forces 8 outstanding loads per wave,
//    stores then drain with per-use vmcnt waits.
//  - Plain stores (V2's nontemporal stores are a regression suspect).
//  - Chunk spans 2 (c,f) rows: f = (2*bx + (j>>1)) & 127 is block-uniform ->
//    fmask is scalar; tmask has only 2 per-thread variants (tv = tid, tid+256).

#define BB 64
#define CC 2
#define FF 128
#define TT 2048
#define VB (CC * FF * (TT / 4))   // 131072 float4 per batch
#define CHUNK 1024                // float4 per block (16 KB)
#define BLOCKS_X (VB / CHUNK)     // 128
#define VPB 4                     // float4 per thread

typedef float f32x4 __attribute__((ext_vector_type(4)));

__global__ __launch_bounds__(256) void specaug_kernel(
    const float* __restrict__ spec,
    const float* __restrict__ apply_u,
    const float* __restrict__ f_width_u,
    const float* __restrict__ f_start_u,
    const float* __restrict__ t_width_u,
    const float* __restrict__ t_start_u,
    const float* __restrict__ noise,
    float* __restrict__ out)
{
    const int b   = blockIdx.y;            // batch: SGPR -> scalar param loads
    const int bx  = blockIdx.x;
    const int tid = threadIdx.x;
    const int base = b * VB + bx * CHUNK + tid;   // float4 index

    const f32x4* __restrict__ sp = (const f32x4*)spec;
    const f32x4* __restrict__ np = (const f32x4*)noise;
    f32x4* __restrict__ op = (f32x4*)out;

    // Scalar (block-uniform) branch: non-applied batches are a straight copy.
    if (apply_u[b] > 0.5f) {
        f32x4 v[VPB];
        #pragma unroll
        for (int j = 0; j < VPB; ++j) v[j] = sp[base + j * 256];
        asm volatile("" ::: "memory");     // keep all loads before stores
        #pragma unroll
        for (int j = 0; j < VPB; ++j) op[base + j * 256] = v[j];
        return;
    }

    // ---- applied path ----
    // Mask params (identical math to reference; freq range needs no clamp:
    // F - w >= 109 > 0; time range clamped to >= 1).
    int fs[2], fw[2], ts[2], tw[2];
    #pragma unroll
    for (int k = 0; k < 2; ++k) {
        fw[k] = (int)floorf(f_width_u[b * 2 + k] * 20.0f);
        fs[k] = (int)floorf(f_start_u[b * 2 + k] * (float)(FF - fw[k]));
        tw[k] = (int)floorf(t_width_u[b * 2 + k] * 40.0f);
        ts[k] = (int)floorf(t_start_u[b * 2 + k] *
                            fmaxf((float)(TT - tw[k]), 1.0f));
    }

    // Time masks: thread touches tv = tid (j even) and tv = tid+256 (j odd).
    bool tm[2][4];
    #pragma unroll
    for (int h = 0; h < 2; ++h) {
        const int t0 = (tid + h * 256) << 2;
        #pragma unroll
        for (int jj = 0; jj < 4; ++jj) {
            const int t = t0 + jj;
            tm[h][jj] = ((t >= ts[0]) & (t < ts[0] + tw[0])) |
                        ((t >= ts[1]) & (t < ts[1] + tw[1]));
        }
    }

    // Freq masks: chunk covers rows 2*bx and 2*bx+1 -> block-uniform.
    bool fm[2];
    #pragma unroll
    for (int r = 0; r < 2; ++r) {
        const int f = (2 * bx + r) & (FF - 1);
        fm[r] = ((f >= fs[0]) & (f < fs[0] + fw[0])) |
                ((f >= fs[1]) & (f < fs[1] + fw[1]));
    }

    // Issue all 8 loads, THEN compute/store (fence stops load sinking).
    f32x4 sv[VPB], nv[VPB];
    #pragma unroll
    for (int j = 0; j < VPB; ++j) sv[j] = sp[base + j * 256];
    #pragma unroll
    for (int j = 0; j < VPB; ++j) nv[j] = np[base + j * 256];
    asm volatile("" ::: "memory");

    #pragma unroll
    for (int j = 0; j < VPB; ++j) {
        const bool fmask = fm[j >> 1];
        const bool* tmj  = tm[j & 1];
        f32x4 o;
        #pragma unroll
        for (int jj = 0; jj < 4; ++jj) {
            const bool keep = !(fmask | tmj[jj]);
            o[jj] = (keep ? sv[j][jj] : 0.0f) + nv[j][jj] * 0.01f;
        }
        op[base + j * 256] = o;
    }
}

extern "C" void kernel_launch(void* const* d_in, const int* in_sizes, int n_in,
                              void* d_out, int out_size, void* d_ws, size_t ws_size,
                              hipStream_t stream) {
    const float* spec      = (const float*)d_in[0];
    const float* apply_u   = (const float*)d_in[1];
    const float* f_width_u = (const float*)d_in[2];
    const float* f_start_u = (const float*)d_in[3];
    const float* t_width_u = (const float*)d_in[4];
    const float* t_start_u = (const float*)d_in[5];
    const float* noise     = (const float*)d_in[6];
    float* out             = (float*)d_out;

    dim3 grid(BLOCKS_X, BB);   // 128 x 64 = 8192 blocks
    specaug_kernel<<<grid, 256, 0, stream>>>(
        spec, apply_u, f_width_u, f_start_u, t_width_u, t_start_u, noise, out);
}